// Round 5
// baseline (147.685 us; speedup 1.0000x reference)
//
#include <hip/hip_runtime.h>
#include <math.h>

// CARAFE upsample: B=8, C=128, H=W=64, S=2, K=5, M=64, n_enc=100 (pad 128)
// NOTE: large fixed floor in dur_us: harness re-poison fill (256MiB ws @
// ~44us, HBM-bound) + out poison + input restore + dozens of tiny reset
// dispatches inside the timed window.
// R10 structure (2 dispatches; R1 measured +3.3us per extra dispatch):
//  K_comp_all: (512 blocks, b,h XCD-chunk swizzled)
//    - stage x[b,:,h,:] to LDS + write bf16 xpad interior row
//    - zero xpad borders for 2 planes/block; a_prep slice (144 elems/block)
//    - 1x1 compress with weights s_loaded DIRECTLY from cw (k-outer/c-inner,
//      contiguous dwordx16 rows; no cwT tensor) -> m_t[b][h][w][mo] bf16
//  K_main: fused encoder(MFMA)+pixelshuffle+softmax->LDS wgt->25-tap
//    reassembly -> out. Identical to the 135.1us-measured R0 kernel.

typedef __attribute__((ext_vector_type(8))) short short8;
typedef __attribute__((ext_vector_type(4))) float floatx4;
typedef __attribute__((ext_vector_type(2))) float v2f;

__device__ __forceinline__ unsigned short f2bf(float f) {
  union { float f; unsigned int u; } v; v.f = f;
  unsigned int u = v.u + 0x7fffu + ((v.u >> 16) & 1u);  // RNE
  return (unsigned short)(u >> 16);
}
__device__ __forceinline__ void unpack2(unsigned int u, float& lo, float& hi) {
  union { unsigned int u; float f; } a, b;
  a.u = u << 16; b.u = u & 0xffff0000u;
  lo = a.f; hi = b.f;
}
__device__ __forceinline__ v2f unpack2v(unsigned int u) {
  union { unsigned int u; float f; } a, b;
  a.u = u << 16; b.u = u & 0xffff0000u;
  return (v2f){a.f, b.f};
}

// ---------------------------------------------------------------------------
// K_comp_all: block (b,h) [XCD-chunk swizzled]. 512 x 256.
//  1) stage x[b,:,h,:] (32KB f32) to LDS, bf16 xpad interior as side effect
//  2) zero xpad borders of planes {2lb, 2lb+1}; a_prep slice [lb*144,+144)
//  3) compress: wave wv owns mo [16wv,16wv+16); x cached in 64 VGPRs/half,
//     weight rows s_loaded contiguous from cw. Same FMA order as before.
//  4) bias + f2bf pack -> LDS transpose (reuse xs) -> b128 m_t stores.
// ---------------------------------------------------------------------------
__global__ __launch_bounds__(256) void k_comp_all(
    const float* __restrict__ x, const float* __restrict__ cw,
    const float* __restrict__ cb, const float* __restrict__ ew,
    unsigned short* __restrict__ m_t, unsigned short* __restrict__ xpad,
    unsigned short* __restrict__ a_prep) {
  __shared__ __align__(16) float xs[128 * 64];  // 32KB; reused as ms after
  const int lb = (((int)blockIdx.x & 7) << 6) | ((int)blockIdx.x >> 3);
  const int b = lb >> 6;
  const int h = lb & 63;
  const int t = (int)threadIdx.x;

  // ---- 1) stage x row + fused xpad interior write ----
  const float* xrow = x + (((size_t)b * 128) * 64 + h) * 64;
  unsigned short* xpd = xpad + (size_t)b * 128 * 4896 + (h + 2) * 72 + 2;
#pragma unroll
  for (int it = 0; it < 32; ++it) {
    int idx = it * 256 + t;
    int c = idx >> 6, w = idx & 63;
    float v = xrow[(size_t)c * 4096 + w];
    xs[idx] = v;
    xpd[(size_t)c * 4896 + w] = f2bf(v);
  }

  // ---- 2a) a_prep slice: idx in [lb*144, lb*144+144) ----
  if (t < 144) {
    int idx = lb * 144 + t;  // [0, 73728)
    int mo = idx & 63;
    int n = (idx >> 6) & 127;
    int tap = idx >> 13;
    float v = (n < 100) ? ew[(n * 64 + mo) * 9 + tap] : 0.f;
    a_prep[idx] = f2bf(v);
  }

  // ---- 2b) xpad borders for planes 2lb, 2lb+1 (800 u32 zeros) ----
  for (int i = t; i < 800; i += 256) {
    int which = (i >= 400);
    int k = i - which * 400;
    unsigned int* pd = (unsigned int*)(xpad + (size_t)(lb * 2 + which) * 4896);
    int u32idx;
    if (k < 72) {
      u32idx = k;                      // rows 0-1 full
    } else if (k < 144) {
      u32idx = 2376 + (k - 72);        // rows 66-67 full
    } else {
      int j = k - 144;                 // [0,256): rows 2..65, 4 u32 each
      int r = 2 + (j >> 2), s = j & 3;
      u32idx = r * 36 + (s ? 32 + s : 0);  // cols {0,1} / {66..71}
    }
    pd[u32idx] = 0u;
  }
  __syncthreads();

  // ---- 3) compress ----
  const int wv = __builtin_amdgcn_readfirstlane(t >> 6);
  const int lane = t & 63;
  const int mo0 = wv * 16;

  float acc[16];
#pragma unroll
  for (int k = 0; k < 16; ++k) acc[k] = 0.f;

  const float* wbase = cw + (size_t)mo0 * 128;  // wave-uniform 16x128 block

  for (int half = 0; half < 2; ++half) {
    float xr[64];
#pragma unroll
    for (int c = 0; c < 64; ++c) xr[c] = xs[(half * 64 + c) * 64 + lane];
#pragma unroll
    for (int kq = 0; kq < 4; ++kq) {
      const float* r0 = wbase + (kq * 4 + 0) * 128 + half * 64;
      const float* r1 = wbase + (kq * 4 + 1) * 128 + half * 64;
      const float* r2 = wbase + (kq * 4 + 2) * 128 + half * 64;
      const float* r3 = wbase + (kq * 4 + 3) * 128 + half * 64;
#pragma unroll
      for (int c = 0; c < 64; ++c) {
        acc[kq * 4 + 0] = fmaf(xr[c], r0[c], acc[kq * 4 + 0]);
        acc[kq * 4 + 1] = fmaf(xr[c], r1[c], acc[kq * 4 + 1]);
        acc[kq * 4 + 2] = fmaf(xr[c], r2[c], acc[kq * 4 + 2]);
        acc[kq * 4 + 3] = fmaf(xr[c], r3[c], acc[kq * 4 + 3]);
      }
    }
  }

#pragma unroll
  for (int k = 0; k < 16; ++k) acc[k] += cb[mo0 + k];

  // ---- 4) pack + transpose + store ----
  __syncthreads();  // all xs reads done; reuse region as ms[64][72]
  unsigned short* ms = (unsigned short*)xs;
#pragma unroll
  for (int k = 0; k < 8; ++k) {
    unsigned int p = ((unsigned int)f2bf(acc[2 * k + 1]) << 16) | f2bf(acc[2 * k]);
    *(unsigned int*)&ms[lane * 72 + mo0 + 2 * k] = p;
  }
  __syncthreads();
#pragma unroll
  for (int rep = 0; rep < 2; ++rep) {
    int idx = t + rep * 256;  // 0..511 -> w = idx>>3 in [0,64)
    uint4 v = *(const uint4*)&ms[(idx >> 3) * 72 + (idx & 7) * 8];
    *(uint4*)&m_t[(size_t)lb * 4096 + idx * 8] = v;
  }
}

// ---------------------------------------------------------------------------
// K_main (fused encoder+softmax+reassemble). Block per (b,h), XCD-chunk
// swizzled so XCD b consumes the m_t/xpad its k_comp_all blocks produced.
// Phase A: bf16 MFMA 3x3 conv (64->128ch), pixelshuffle+softmax -> LDS wgt_s.
// Phase B: out[b][c][2h+oh][ow] = sum_ij xpad[b][c][h+i][w+j]*wgt_s[oh][ij][ow]
// LDS union: m_s (27.6KB) / raw (33.8KB) / wgt_s (12.8KB) share one region.
// ---------------------------------------------------------------------------
__global__ __launch_bounds__(256) void k_main(
    const unsigned short* __restrict__ m_t, const unsigned short* __restrict__ a_prep,
    const float* __restrict__ eb, const unsigned short* __restrict__ xpad,
    float* __restrict__ out) {
  __shared__ __align__(16) float raw[128 * 66];   // 33.8KB union
  unsigned short* m_s = (unsigned short*)raw;     // [dh][w][mo pad72] 27.6KB
  unsigned short* wgt_s = (unsigned short*)raw;   // [oh2][kk25][ow128] 12.8KB
  const int lb = (((int)blockIdx.x & 7) << 6) | ((int)blockIdx.x >> 3);
  const int b = lb >> 6;
  const int h = lb & 63;
  const int t = (int)threadIdx.x;

  // ---- Phase A: stage m rows h-1,h,h+1 ----
  for (int idx = t; idx < 3 * 64 * 8; idx += 256) {
    int r = idx >> 9;
    int rem = idx & 511;
    int w = rem >> 3, u = rem & 7;
    int hh = h + r - 1;
    uint4 val = make_uint4(0u, 0u, 0u, 0u);
    if (hh >= 0 && hh < 64)
      val = *(const uint4*)&m_t[(((b * 64 + hh) * 64 + w) * 64) + u * 8];
    *(uint4*)&m_s[(r * 64 + w) * 72 + u * 8] = val;
  }
  __syncthreads();

  const int wave = t >> 6, lane = t & 63;
  const int quad = lane >> 4, col = lane & 15;
  const int nbase = wave * 32;

  const floatx4 z4 = {0.f, 0.f, 0.f, 0.f};
  floatx4 acc[2][4];
#pragma unroll
  for (int i = 0; i < 2; ++i)
#pragma unroll
    for (int p = 0; p < 4; ++p) acc[i][p] = z4;

  const short8 z8 = {0, 0, 0, 0, 0, 0, 0, 0};

#pragma unroll
  for (int tap = 0; tap < 9; ++tap) {
    const int dh = tap / 3, dw = tap % 3;
#pragma unroll
    for (int half = 0; half < 2; ++half) {
      const int mo0 = half * 32;
      short8 a0 = *(const short8*)&a_prep[((tap * 128 + nbase + col) * 64) + mo0 + quad * 8];
      short8 a1 = *(const short8*)&a_prep[((tap * 128 + nbase + 16 + col) * 64) + mo0 + quad * 8];
#pragma unroll
      for (int p = 0; p < 4; ++p) {
        int wsrc = p * 16 + col + dw - 1;
        int wc = min(max(wsrc, 0), 63);
        short8 bf = *(const short8*)&m_s[(dh * 64 + wc) * 72 + mo0 + quad * 8];
        if (wsrc < 0 || wsrc > 63) bf = z8;
        acc[0][p] = __builtin_amdgcn_mfma_f32_16x16x32_bf16(a0, bf, acc[0][p], 0, 0, 0);
        acc[1][p] = __builtin_amdgcn_mfma_f32_16x16x32_bf16(a1, bf, acc[1][p], 0, 0, 0);
      }
    }
  }

  __syncthreads();  // m_s dead; raw takes over the union
#pragma unroll
  for (int i = 0; i < 2; ++i)
#pragma unroll
    for (int p = 0; p < 4; ++p)
#pragma unroll
      for (int r = 0; r < 4; ++r)
        raw[(nbase + i * 16 + quad * 4 + r) * 66 + p * 16 + col] = acc[i][p][r];
  __syncthreads();

  // softmax over kk (n = kk*4+q), q = wave, px = lane
  const int q = wave;
  float v[25];
  float mx = -1e30f;
#pragma unroll
  for (int kk = 0; kk < 25; ++kk) {
    v[kk] = raw[(kk * 4 + q) * 66 + lane] + eb[kk * 4 + q];
    mx = fmaxf(mx, v[kk]);
  }
  float s = 0.f;
#pragma unroll
  for (int kk = 0; kk < 25; ++kk) {
    v[kk] = __expf(v[kk] - mx);
    s += v[kk];
  }
  float inv = 1.f / s;

  __syncthreads();  // raw reads done; wgt_s takes over the union
  {
    const int ohl = q >> 1;
    const int owp = 2 * lane + (q & 1);
#pragma unroll
    for (int kk = 0; kk < 25; ++kk)
      wgt_s[(ohl * 25 + kk) * 128 + owp] = f2bf(v[kk] * inv);
  }
  __syncthreads();

  // ---- Phase B: reassembly, both channel halves ----
  const int wg = t & 15;
  const int cg = t >> 4;
  const int w0 = wg * 4;

  for (int chalf = 0; chalf < 2; ++chalf) {
    const int c0 = chalf * 64 + cg * 4;
    const unsigned short* xb =
        xpad + ((size_t)(b * 128 + c0) * 4896) + h * 72 + w0;

    v2f accB[2][4][4];  // [oh][ch][k]
#pragma unroll
    for (int oh = 0; oh < 2; ++oh)
#pragma unroll
      for (int ch = 0; ch < 4; ++ch)
#pragma unroll
        for (int k = 0; k < 4; ++k) accB[oh][ch][k] = (v2f){0.f, 0.f};

    for (int i = 0; i < 5; ++i) {
      float xr[4][8];
#pragma unroll
      for (int ch = 0; ch < 4; ++ch) {
        uint4 rawv = *(const uint4*)(xb + ch * 4896 + i * 72);
        unpack2(rawv.x, xr[ch][0], xr[ch][1]);
        unpack2(rawv.y, xr[ch][2], xr[ch][3]);
        unpack2(rawv.z, xr[ch][4], xr[ch][5]);
        unpack2(rawv.w, xr[ch][6], xr[ch][7]);
      }
#pragma unroll
      for (int j = 0; j < 5; ++j) {
        const int ij = i * 5 + j;
#pragma unroll
        for (int oh = 0; oh < 2; ++oh) {
          uint4 wr = *(const uint4*)&wgt_s[(oh * 25 + ij) * 128 + w0 * 2];
          v2f wp[4];
          wp[0] = unpack2v(wr.x);
          wp[1] = unpack2v(wr.y);
          wp[2] = unpack2v(wr.z);
          wp[3] = unpack2v(wr.w);
#pragma unroll
          for (int k = 0; k < 4; ++k)
#pragma unroll
            for (int ch = 0; ch < 4; ++ch) {
              float xv = xr[ch][k + j];
              v2f xvv = {xv, xv};
              accB[oh][ch][k] += xvv * wp[k];  // v_pk_fma_f32
            }
        }
      }
    }

#pragma unroll
    for (int ch = 0; ch < 4; ++ch)
#pragma unroll
      for (int oh = 0; oh < 2; ++oh) {
        float* orow =
            out + ((size_t)(b * 128 + c0 + ch) * 128 + (2 * h + oh)) * 128 + w0 * 2;
        float4 f0 = make_float4(accB[oh][ch][0].x, accB[oh][ch][0].y,
                                accB[oh][ch][1].x, accB[oh][ch][1].y);
        float4 f1 = make_float4(accB[oh][ch][2].x, accB[oh][ch][2].y,
                                accB[oh][ch][3].x, accB[oh][ch][3].y);
        *(float4*)orow = f0;
        *(float4*)(orow + 4) = f1;
      }
  }
}

// ---------------------------------------------------------------------------
extern "C" void kernel_launch(void* const* d_in, const int* in_sizes, int n_in,
                              void* d_out, int out_size, void* d_ws, size_t ws_size,
                              hipStream_t stream) {
  (void)in_sizes; (void)n_in; (void)out_size; (void)ws_size;
  const float* x  = (const float*)d_in[0];
  const float* cw = (const float*)d_in[1];
  const float* cb = (const float*)d_in[2];
  const float* ew = (const float*)d_in[3];
  const float* eb = (const float*)d_in[4];
  float* out = (float*)d_out;

  char* wsb = (char*)d_ws;
  unsigned short* m_t    = (unsigned short*)(wsb);               // 4,194,304 B
  unsigned short* a_prep = (unsigned short*)(wsb + 4194304);     //   147,456 B
  unsigned short* xpad   = (unsigned short*)(wsb + 4341760);     // 10,027,008 B

  k_comp_all<<<dim3(512), dim3(256), 0, stream>>>(x, cw, cb, ew, m_t, xpad, a_prep);
  k_main<<<dim3(512), dim3(256), 0, stream>>>(m_t, a_prep, eb, xpad, out);
}

// Round 6
// 146.169 us; speedup vs baseline: 1.0104x; 1.0104x over previous
//
#include <hip/hip_runtime.h>
#include <math.h>

// CARAFE upsample: B=8, C=128, H=W=64, S=2, K=5, M=64, n_enc=100 (pad 128)
// NOTE: ~58us of dur_us is harness re-poison fill (256MiB ws @ ~44us) +
// out-buffer poison + input restore inside the timed window — fixed floor.
// R11 = measured-best R0 structure (135.1us) + Phase-B load pipelining.
// History: R1 split k_main (+3.3us), R4 merged prep+compress (+12.6us) —
// both regressed; 3-dispatch structure is the local optimum. This round
// only reorders k_main Phase-B global loads (early-issue before the wgt
// barriers + rolling one-row-ahead prefetch). Bit-identical numerics.
//  K_prep:     ew->a_prep bf16, cw->cwT, xpad border zeros (tiny)
//  K_comp_pad: x staged to LDS once -> xpad interior bf16 + 1x1 compress
//              -> m_t[b][h][w][mo] bf16. XCD-chunk swizzled.
//  K_main:     bf16 MFMA encoder conv + pixelshuffle + softmax -> LDS wgt
//              -> fused reassembly (25-tap weighted sum) -> out.

typedef __attribute__((ext_vector_type(8))) short short8;
typedef __attribute__((ext_vector_type(4))) float floatx4;
typedef __attribute__((ext_vector_type(2))) float v2f;

__device__ __forceinline__ unsigned short f2bf(float f) {
  union { float f; unsigned int u; } v; v.f = f;
  unsigned int u = v.u + 0x7fffu + ((v.u >> 16) & 1u);  // RNE
  return (unsigned short)(u >> 16);
}
__device__ __forceinline__ void unpack2(unsigned int u, float& lo, float& hi) {
  union { unsigned int u; float f; } a, b;
  a.u = u << 16; b.u = u & 0xffff0000u;
  lo = a.f; hi = b.f;
}
__device__ __forceinline__ v2f unpack2v(unsigned int u) {
  union { unsigned int u; float f; } a, b;
  a.u = u << 16; b.u = u & 0xffff0000u;
  return (v2f){a.f, b.f};
}

// ---------------------------------------------------------------------------
// K_prep: blocks [0,320): a_prep[tap][n][mo] = bf16(ew[n][mo][tap]) (n>=100->0)
//                         cwT[c][mo] = cw[mo][c]
//         blocks [320,832): zero xpad borders (2 planes per block).
// ---------------------------------------------------------------------------
__global__ __launch_bounds__(256) void k_prep(
    const float* __restrict__ ew, const float* __restrict__ cw,
    unsigned short* __restrict__ a_prep, float* __restrict__ cwT,
    unsigned short* __restrict__ xpad) {
  const int blk = blockIdx.x;
  if (blk < 320) {
    int idx = blk * 256 + (int)threadIdx.x;  // [0, 81920)
    if (idx < 9 * 128 * 64) {
      int mo = idx & 63;
      int n = (idx >> 6) & 127;
      int tap = idx >> 13;
      float v = (n < 100) ? ew[(n * 64 + mo) * 9 + tap] : 0.f;
      a_prep[idx] = f2bf(v);
    } else {
      int r = idx - 9 * 128 * 64;  // [0, 8192)
      int c = r >> 6, mo = r & 63;
      cwT[c * 64 + mo] = cw[mo * 128 + c];
    }
  } else {
    int local = blk - 320;  // [0,512): planes 2*local, 2*local+1
    for (int i = threadIdx.x; i < 800; i += 256) {
      int which = (i >= 400);
      int k = i - which * 400;
      unsigned int* pd =
          (unsigned int*)(xpad + (size_t)(local * 2 + which) * 4896);
      int u32idx;
      if (k < 72) {
        u32idx = k;                      // rows 0-1 full
      } else if (k < 144) {
        u32idx = 2376 + (k - 72);        // rows 66-67 full
      } else {
        int j = k - 144;                 // [0,256): rows 2..65, 4 u32 each
        int r = 2 + (j >> 2), s = j & 3;
        u32idx = r * 36 + (s ? 32 + s : 0);  // cols {0,1} / {66..71}
      }
      pd[u32idx] = 0u;
    }
  }
}

// ---------------------------------------------------------------------------
// K_comp_pad: block (b,h) [XCD-chunk swizzled]. 512 x 256.
//  Stage x[b,:,h,:] (32KB f32) to LDS once, writing bf16 xpad interior as a
//  side effect. Then 1x1 compress: wave wv owns mo [16wv,16wv+16) via SGPR
//  weights; x broadcast from LDS. Epilogue: LDS transpose -> b128 stores.
// ---------------------------------------------------------------------------
__global__ __launch_bounds__(256) void k_comp_pad(
    const float* __restrict__ x, const float* __restrict__ cwT,
    const float* __restrict__ cb, unsigned short* __restrict__ m_t,
    unsigned short* __restrict__ xpad) {
  __shared__ __align__(16) float xs[128 * 64];  // 32KB; reused as ms after
  const int lb = (((int)blockIdx.x & 7) << 6) | ((int)blockIdx.x >> 3);
  const int b = lb >> 6;
  const int h = lb & 63;
  const int t = (int)threadIdx.x;

  const float* xrow = x + (((size_t)b * 128) * 64 + h) * 64;
  unsigned short* xpd = xpad + (size_t)b * 128 * 4896 + (h + 2) * 72 + 2;
#pragma unroll
  for (int it = 0; it < 32; ++it) {
    int idx = it * 256 + t;
    int c = idx >> 6, w = idx & 63;
    float v = xrow[(size_t)c * 4096 + w];
    xs[idx] = v;
    xpd[(size_t)c * 4896 + w] = f2bf(v);
  }
  __syncthreads();

  const int wv = __builtin_amdgcn_readfirstlane(t >> 6);
  const int lane = t & 63;
  const int mo0 = wv * 16;

  float acc[16];
#pragma unroll
  for (int k = 0; k < 16; ++k) acc[k] = 0.f;

  const float* wp = cwT + mo0;  // wave-uniform -> s_loads

#pragma unroll 4
  for (int c = 0; c < 128; ++c) {
    float xv = xs[c * 64 + lane];
#pragma unroll
    for (int k = 0; k < 16; ++k)
      acc[k] = fmaf(xv, wp[c * 64 + k], acc[k]);
  }

#pragma unroll
  for (int k = 0; k < 16; ++k) acc[k] += cb[mo0 + k];

  __syncthreads();  // all xs reads done; reuse region as ms[64][72]
  unsigned short* ms = (unsigned short*)xs;
#pragma unroll
  for (int k = 0; k < 8; ++k) {
    unsigned int p = ((unsigned int)f2bf(acc[2 * k + 1]) << 16) | f2bf(acc[2 * k]);
    *(unsigned int*)&ms[lane * 72 + mo0 + 2 * k] = p;
  }
  __syncthreads();
#pragma unroll
  for (int rep = 0; rep < 2; ++rep) {
    int idx = t + rep * 256;  // 0..511 -> w = idx>>3 in [0,64)
    uint4 v = *(const uint4*)&ms[(idx >> 3) * 72 + (idx & 7) * 8];
    *(uint4*)&m_t[(size_t)lb * 4096 + idx * 8] = v;
  }
}

// ---------------------------------------------------------------------------
// K_main (fused encoder+softmax+reassemble). Block per (b,h), XCD-chunk
// swizzled so XCD b consumes the m_t/xpad its k_comp_pad blocks produced.
// Phase A: bf16 MFMA 3x3 conv (64->128ch), pixelshuffle+softmax -> LDS wgt_s.
// Phase B: out[b][c][2h+oh][ow] = sum_ij xpad[b][c][h+i][w+j]*wgt_s[oh][ij][ow]
//   Pipelined: row-0 x loads (both chalves) issued BEFORE the wgt barriers
//   (compiler can't hoist globals across __syncthreads); one-row-ahead
//   rolling prefetch inside the 5-row loop, cross-chalf handoff at i=4.
// LDS union: m_s (27.6KB) / raw (33.8KB) / wgt_s (12.8KB) share one region.
// ---------------------------------------------------------------------------
__global__ __launch_bounds__(256) void k_main(
    const unsigned short* __restrict__ m_t, const unsigned short* __restrict__ a_prep,
    const float* __restrict__ eb, const unsigned short* __restrict__ xpad,
    float* __restrict__ out) {
  __shared__ __align__(16) float raw[128 * 66];   // 33.8KB union
  unsigned short* m_s = (unsigned short*)raw;     // [dh][w][mo pad72] 27.6KB
  unsigned short* wgt_s = (unsigned short*)raw;   // [oh2][kk25][ow128] 12.8KB
  const int lb = (((int)blockIdx.x & 7) << 6) | ((int)blockIdx.x >> 3);
  const int b = lb >> 6;
  const int h = lb & 63;
  const int t = (int)threadIdx.x;

  // ---- Phase A: stage m rows h-1,h,h+1 ----
  for (int idx = t; idx < 3 * 64 * 8; idx += 256) {
    int r = idx >> 9;
    int rem = idx & 511;
    int w = rem >> 3, u = rem & 7;
    int hh = h + r - 1;
    uint4 val = make_uint4(0u, 0u, 0u, 0u);
    if (hh >= 0 && hh < 64)
      val = *(const uint4*)&m_t[(((b * 64 + hh) * 64 + w) * 64) + u * 8];
    *(uint4*)&m_s[(r * 64 + w) * 72 + u * 8] = val;
  }
  __syncthreads();

  const int wave = t >> 6, lane = t & 63;
  const int quad = lane >> 4, col = lane & 15;
  const int nbase = wave * 32;

  const floatx4 z4 = {0.f, 0.f, 0.f, 0.f};
  floatx4 acc[2][4];
#pragma unroll
  for (int i = 0; i < 2; ++i)
#pragma unroll
    for (int p = 0; p < 4; ++p) acc[i][p] = z4;

  const short8 z8 = {0, 0, 0, 0, 0, 0, 0, 0};

#pragma unroll
  for (int tap = 0; tap < 9; ++tap) {
    const int dh = tap / 3, dw = tap % 3;
#pragma unroll
    for (int half = 0; half < 2; ++half) {
      const int mo0 = half * 32;
      short8 a0 = *(const short8*)&a_prep[((tap * 128 + nbase + col) * 64) + mo0 + quad * 8];
      short8 a1 = *(const short8*)&a_prep[((tap * 128 + nbase + 16 + col) * 64) + mo0 + quad * 8];
#pragma unroll
      for (int p = 0; p < 4; ++p) {
        int wsrc = p * 16 + col + dw - 1;
        int wc = min(max(wsrc, 0), 63);
        short8 bf = *(const short8*)&m_s[(dh * 64 + wc) * 72 + mo0 + quad * 8];
        if (wsrc < 0 || wsrc > 63) bf = z8;
        acc[0][p] = __builtin_amdgcn_mfma_f32_16x16x32_bf16(a0, bf, acc[0][p], 0, 0, 0);
        acc[1][p] = __builtin_amdgcn_mfma_f32_16x16x32_bf16(a1, bf, acc[1][p], 0, 0, 0);
      }
    }
  }

  __syncthreads();  // m_s dead; raw takes over the union
#pragma unroll
  for (int i = 0; i < 2; ++i)
#pragma unroll
    for (int p = 0; p < 4; ++p)
#pragma unroll
      for (int r = 0; r < 4; ++r)
        raw[(nbase + i * 16 + quad * 4 + r) * 66 + p * 16 + col] = acc[i][p][r];
  __syncthreads();

  // softmax over kk (n = kk*4+q), q = wave, px = lane
  const int q = wave;
  float v[25];
  float mx = -1e30f;
#pragma unroll
  for (int kk = 0; kk < 25; ++kk) {
    v[kk] = raw[(kk * 4 + q) * 66 + lane] + eb[kk * 4 + q];
    mx = fmaxf(mx, v[kk]);
  }
  float s = 0.f;
#pragma unroll
  for (int kk = 0; kk < 25; ++kk) {
    v[kk] = __expf(v[kk] - mx);
    s += v[kk];
  }
  float inv = 1.f / s;

  // ---- Phase B addressing + EARLY row-0 loads (both chalves): these land
  // while the two barriers + wgt_s writes drain. ----
  const int wg = t & 15;
  const int cg = t >> 4;
  const int w0 = wg * 4;
  const unsigned short* xb0 =
      xpad + ((size_t)(b * 128 + cg * 4) * 4896) + h * 72 + w0;
  const unsigned short* xb1 = xb0 + (size_t)64 * 4896;

  uint4 cur[4], pre1[4], r1[4];
#pragma unroll
  for (int ch = 0; ch < 4; ++ch) {
    cur[ch] = *(const uint4*)(xb0 + (size_t)ch * 4896);
    pre1[ch] = *(const uint4*)(xb1 + (size_t)ch * 4896);
  }

  __syncthreads();  // raw reads done; wgt_s takes over the union
  {
    const int ohl = q >> 1;
    const int owp = 2 * lane + (q & 1);
#pragma unroll
    for (int kk = 0; kk < 25; ++kk)
      wgt_s[(ohl * 25 + kk) * 128 + owp] = f2bf(v[kk] * inv);
  }
  __syncthreads();

  // ---- Phase B: reassembly, pipelined ----
  v2f accB[2][4][4];  // [oh][ch][k]

  // ================= chalf 0 (c0 = cg*4) =================
  {
#pragma unroll
    for (int oh = 0; oh < 2; ++oh)
#pragma unroll
      for (int ch = 0; ch < 4; ++ch)
#pragma unroll
        for (int k = 0; k < 4; ++k) accB[oh][ch][k] = (v2f){0.f, 0.f};

#pragma unroll
    for (int i = 0; i < 5; ++i) {
      float xr[4][8];
#pragma unroll
      for (int ch = 0; ch < 4; ++ch) {
        unpack2(cur[ch].x, xr[ch][0], xr[ch][1]);
        unpack2(cur[ch].y, xr[ch][2], xr[ch][3]);
        unpack2(cur[ch].z, xr[ch][4], xr[ch][5]);
        unpack2(cur[ch].w, xr[ch][6], xr[ch][7]);
      }
      if (i < 4) {
#pragma unroll
        for (int ch = 0; ch < 4; ++ch)
          cur[ch] = *(const uint4*)(xb0 + (size_t)ch * 4896 + (i + 1) * 72);
      } else {
#pragma unroll
        for (int ch = 0; ch < 4; ++ch)  // prefetch chalf1 row 1
          r1[ch] = *(const uint4*)(xb1 + (size_t)ch * 4896 + 72);
      }
#pragma unroll
      for (int j = 0; j < 5; ++j) {
        const int ij = i * 5 + j;
#pragma unroll
        for (int oh = 0; oh < 2; ++oh) {
          uint4 wr = *(const uint4*)&wgt_s[(oh * 25 + ij) * 128 + w0 * 2];
          v2f wp[4];
          wp[0] = unpack2v(wr.x);
          wp[1] = unpack2v(wr.y);
          wp[2] = unpack2v(wr.z);
          wp[3] = unpack2v(wr.w);
#pragma unroll
          for (int k = 0; k < 4; ++k)
#pragma unroll
            for (int ch = 0; ch < 4; ++ch) {
              float xv = xr[ch][k + j];
              v2f xvv = {xv, xv};
              accB[oh][ch][k] += xvv * wp[k];  // v_pk_fma_f32
            }
        }
      }
    }

    const int c0 = cg * 4;
#pragma unroll
    for (int ch = 0; ch < 4; ++ch)
#pragma unroll
      for (int oh = 0; oh < 2; ++oh) {
        float* orow =
            out + ((size_t)(b * 128 + c0 + ch) * 128 + (2 * h + oh)) * 128 + w0 * 2;
        float4 f0 = make_float4(accB[oh][ch][0].x, accB[oh][ch][0].y,
                                accB[oh][ch][1].x, accB[oh][ch][1].y);
        float4 f1 = make_float4(accB[oh][ch][2].x, accB[oh][ch][2].y,
                                accB[oh][ch][3].x, accB[oh][ch][3].y);
        *(float4*)orow = f0;
        *(float4*)(orow + 4) = f1;
      }
  }

  // ================= chalf 1 (c0 = 64 + cg*4) =================
  {
#pragma unroll
    for (int oh = 0; oh < 2; ++oh)
#pragma unroll
      for (int ch = 0; ch < 4; ++ch)
#pragma unroll
        for (int k = 0; k < 4; ++k) accB[oh][ch][k] = (v2f){0.f, 0.f};

    // cur = row0 (early-loaded), r1 = row1 (prefetched during chalf0 i=4)
#pragma unroll
    for (int ch = 0; ch < 4; ++ch) cur[ch] = pre1[ch];

#pragma unroll
    for (int i = 0; i < 5; ++i) {
      float xr[4][8];
#pragma unroll
      for (int ch = 0; ch < 4; ++ch) {
        unpack2(cur[ch].x, xr[ch][0], xr[ch][1]);
        unpack2(cur[ch].y, xr[ch][2], xr[ch][3]);
        unpack2(cur[ch].z, xr[ch][4], xr[ch][5]);
        unpack2(cur[ch].w, xr[ch][6], xr[ch][7]);
      }
      if (i < 4) {
#pragma unroll
        for (int ch = 0; ch < 4; ++ch) cur[ch] = r1[ch];
      }
      if (i < 3) {
#pragma unroll
        for (int ch = 0; ch < 4; ++ch)
          r1[ch] = *(const uint4*)(xb1 + (size_t)ch * 4896 + (i + 2) * 72);
      }
#pragma unroll
      for (int j = 0; j < 5; ++j) {
        const int ij = i * 5 + j;
#pragma unroll
        for (int oh = 0; oh < 2; ++oh) {
          uint4 wr = *(const uint4*)&wgt_s[(oh * 25 + ij) * 128 + w0 * 2];
          v2f wp[4];
          wp[0] = unpack2v(wr.x);
          wp[1] = unpack2v(wr.y);
          wp[2] = unpack2v(wr.z);
          wp[3] = unpack2v(wr.w);
#pragma unroll
          for (int k = 0; k < 4; ++k)
#pragma unroll
            for (int ch = 0; ch < 4; ++ch) {
              float xv = xr[ch][k + j];
              v2f xvv = {xv, xv};
              accB[oh][ch][k] += xvv * wp[k];  // v_pk_fma_f32
            }
        }
      }
    }

    const int c0 = 64 + cg * 4;
#pragma unroll
    for (int ch = 0; ch < 4; ++ch)
#pragma unroll
      for (int oh = 0; oh < 2; ++oh) {
        float* orow =
            out + ((size_t)(b * 128 + c0 + ch) * 128 + (2 * h + oh)) * 128 + w0 * 2;
        float4 f0 = make_float4(accB[oh][ch][0].x, accB[oh][ch][0].y,
                                accB[oh][ch][1].x, accB[oh][ch][1].y);
        float4 f1 = make_float4(accB[oh][ch][2].x, accB[oh][ch][2].y,
                                accB[oh][ch][3].x, accB[oh][ch][3].y);
        *(float4*)orow = f0;
        *(float4*)(orow + 4) = f1;
      }
  }
}

// ---------------------------------------------------------------------------
extern "C" void kernel_launch(void* const* d_in, const int* in_sizes, int n_in,
                              void* d_out, int out_size, void* d_ws, size_t ws_size,
                              hipStream_t stream) {
  (void)in_sizes; (void)n_in; (void)out_size; (void)ws_size;
  const float* x  = (const float*)d_in[0];
  const float* cw = (const float*)d_in[1];
  const float* cb = (const float*)d_in[2];
  const float* ew = (const float*)d_in[3];
  const float* eb = (const float*)d_in[4];
  float* out = (float*)d_out;

  char* wsb = (char*)d_ws;
  unsigned short* m_t    = (unsigned short*)(wsb);               // 4,194,304 B
  unsigned short* a_prep = (unsigned short*)(wsb + 4194304);     //   147,456 B
  unsigned short* xpad   = (unsigned short*)(wsb + 4341760);     // 10,027,008 B
  float*          cwT    = (float*)(wsb + 14368768);             //    32,768 B

  k_prep<<<dim3(832), dim3(256), 0, stream>>>(ew, cw, a_prep, cwT, xpad);
  k_comp_pad<<<dim3(512), dim3(256), 0, stream>>>(x, cwT, cb, m_t, xpad);
  k_main<<<dim3(512), dim3(256), 0, stream>>>(m_t, a_prep, eb, xpad, out);
}

// Round 7
// 134.681 us; speedup vs baseline: 1.0966x; 1.0853x over previous
//
#include <hip/hip_runtime.h>
#include <math.h>

// CARAFE upsample: B=8, C=128, H=W=64, S=2, K=5, M=64, n_enc=100 (pad 128)
// NOTE: ~58us of dur_us is harness re-poison fill (256MiB ws @ ~44us) +
// out-buffer poison + input restore inside the timed window — fixed floor.
// R12 = byte-exact revert to R0 (measured 135.1us, session best).
// Ledger: R1 split k_main (+3.3us), R4 merged prep+compress (+12.6us),
// R5 Phase-B prefetch (+11us, VGPR 256 -> 1 block/CU, k_main 110us).
// All structural perturbations regressed; this 3-dispatch structure with
// XCD-chunk swizzle is the measured local optimum.
//  K_prep:     ew->a_prep bf16, cw->cwT, xpad border zeros (tiny)
//  K_comp_pad: x staged to LDS once -> xpad interior bf16 + 1x1 compress
//              -> m_t[b][h][w][mo] bf16. XCD-chunk swizzled.
//  K_main:     bf16 MFMA encoder conv + pixelshuffle + softmax -> LDS wgt
//              -> fused reassembly (25-tap weighted sum) -> out.

typedef __attribute__((ext_vector_type(8))) short short8;
typedef __attribute__((ext_vector_type(4))) float floatx4;
typedef __attribute__((ext_vector_type(2))) float v2f;

__device__ __forceinline__ unsigned short f2bf(float f) {
  union { float f; unsigned int u; } v; v.f = f;
  unsigned int u = v.u + 0x7fffu + ((v.u >> 16) & 1u);  // RNE
  return (unsigned short)(u >> 16);
}
__device__ __forceinline__ void unpack2(unsigned int u, float& lo, float& hi) {
  union { unsigned int u; float f; } a, b;
  a.u = u << 16; b.u = u & 0xffff0000u;
  lo = a.f; hi = b.f;
}
__device__ __forceinline__ v2f unpack2v(unsigned int u) {
  union { unsigned int u; float f; } a, b;
  a.u = u << 16; b.u = u & 0xffff0000u;
  return (v2f){a.f, b.f};
}

// ---------------------------------------------------------------------------
// K_prep: blocks [0,320): a_prep[tap][n][mo] = bf16(ew[n][mo][tap]) (n>=100->0)
//                         cwT[c][mo] = cw[mo][c]
//         blocks [320,832): zero xpad borders (2 planes per block).
// ---------------------------------------------------------------------------
__global__ __launch_bounds__(256) void k_prep(
    const float* __restrict__ ew, const float* __restrict__ cw,
    unsigned short* __restrict__ a_prep, float* __restrict__ cwT,
    unsigned short* __restrict__ xpad) {
  const int blk = blockIdx.x;
  if (blk < 320) {
    int idx = blk * 256 + (int)threadIdx.x;  // [0, 81920)
    if (idx < 9 * 128 * 64) {
      int mo = idx & 63;
      int n = (idx >> 6) & 127;
      int tap = idx >> 13;
      float v = (n < 100) ? ew[(n * 64 + mo) * 9 + tap] : 0.f;
      a_prep[idx] = f2bf(v);
    } else {
      int r = idx - 9 * 128 * 64;  // [0, 8192)
      int c = r >> 6, mo = r & 63;
      cwT[c * 64 + mo] = cw[mo * 128 + c];
    }
  } else {
    int local = blk - 320;  // [0,512): planes 2*local, 2*local+1
    for (int i = threadIdx.x; i < 800; i += 256) {
      int which = (i >= 400);
      int k = i - which * 400;
      unsigned int* pd =
          (unsigned int*)(xpad + (size_t)(local * 2 + which) * 4896);
      int u32idx;
      if (k < 72) {
        u32idx = k;                      // rows 0-1 full
      } else if (k < 144) {
        u32idx = 2376 + (k - 72);        // rows 66-67 full
      } else {
        int j = k - 144;                 // [0,256): rows 2..65, 4 u32 each
        int r = 2 + (j >> 2), s = j & 3;
        u32idx = r * 36 + (s ? 32 + s : 0);  // cols {0,1} / {66..71}
      }
      pd[u32idx] = 0u;
    }
  }
}

// ---------------------------------------------------------------------------
// K_comp_pad: block (b,h) [XCD-chunk swizzled]. 512 x 256.
//  Stage x[b,:,h,:] (32KB f32) to LDS once, writing bf16 xpad interior as a
//  side effect. Then 1x1 compress: wave wv owns mo [16wv,16wv+16) via SGPR
//  weights; x broadcast from LDS. Epilogue: LDS transpose -> b128 stores.
// ---------------------------------------------------------------------------
__global__ __launch_bounds__(256) void k_comp_pad(
    const float* __restrict__ x, const float* __restrict__ cwT,
    const float* __restrict__ cb, unsigned short* __restrict__ m_t,
    unsigned short* __restrict__ xpad) {
  __shared__ __align__(16) float xs[128 * 64];  // 32KB; reused as ms after
  const int lb = (((int)blockIdx.x & 7) << 6) | ((int)blockIdx.x >> 3);
  const int b = lb >> 6;
  const int h = lb & 63;
  const int t = (int)threadIdx.x;

  const float* xrow = x + (((size_t)b * 128) * 64 + h) * 64;
  unsigned short* xpd = xpad + (size_t)b * 128 * 4896 + (h + 2) * 72 + 2;
#pragma unroll
  for (int it = 0; it < 32; ++it) {
    int idx = it * 256 + t;
    int c = idx >> 6, w = idx & 63;
    float v = xrow[(size_t)c * 4096 + w];
    xs[idx] = v;
    xpd[(size_t)c * 4896 + w] = f2bf(v);
  }
  __syncthreads();

  const int wv = __builtin_amdgcn_readfirstlane(t >> 6);
  const int lane = t & 63;
  const int mo0 = wv * 16;

  float acc[16];
#pragma unroll
  for (int k = 0; k < 16; ++k) acc[k] = 0.f;

  const float* wp = cwT + mo0;  // wave-uniform -> s_loads

#pragma unroll 4
  for (int c = 0; c < 128; ++c) {
    float xv = xs[c * 64 + lane];
#pragma unroll
    for (int k = 0; k < 16; ++k)
      acc[k] = fmaf(xv, wp[c * 64 + k], acc[k]);
  }

#pragma unroll
  for (int k = 0; k < 16; ++k) acc[k] += cb[mo0 + k];

  __syncthreads();  // all xs reads done; reuse region as ms[64][72]
  unsigned short* ms = (unsigned short*)xs;
#pragma unroll
  for (int k = 0; k < 8; ++k) {
    unsigned int p = ((unsigned int)f2bf(acc[2 * k + 1]) << 16) | f2bf(acc[2 * k]);
    *(unsigned int*)&ms[lane * 72 + mo0 + 2 * k] = p;
  }
  __syncthreads();
#pragma unroll
  for (int rep = 0; rep < 2; ++rep) {
    int idx = t + rep * 256;  // 0..511 -> w = idx>>3 in [0,64)
    uint4 v = *(const uint4*)&ms[(idx >> 3) * 72 + (idx & 7) * 8];
    *(uint4*)&m_t[(size_t)lb * 4096 + idx * 8] = v;
  }
}

// ---------------------------------------------------------------------------
// K_main (fused encoder+softmax+reassemble). Block per (b,h), XCD-chunk
// swizzled so XCD b consumes the m_t/xpad its k_comp_pad blocks produced.
// Phase A: bf16 MFMA 3x3 conv (64->128ch), pixelshuffle+softmax -> LDS wgt_s.
// Phase B: out[b][c][2h+oh][ow] = sum_ij xpad[b][c][h+i][w+j]*wgt_s[oh][ij][ow]
// LDS union: m_s (27.6KB) / raw (33.8KB) / wgt_s (12.8KB) share one region.
// ---------------------------------------------------------------------------
__global__ __launch_bounds__(256) void k_main(
    const unsigned short* __restrict__ m_t, const unsigned short* __restrict__ a_prep,
    const float* __restrict__ eb, const unsigned short* __restrict__ xpad,
    float* __restrict__ out) {
  __shared__ __align__(16) float raw[128 * 66];   // 33.8KB union
  unsigned short* m_s = (unsigned short*)raw;     // [dh][w][mo pad72] 27.6KB
  unsigned short* wgt_s = (unsigned short*)raw;   // [oh2][kk25][ow128] 12.8KB
  const int lb = (((int)blockIdx.x & 7) << 6) | ((int)blockIdx.x >> 3);
  const int b = lb >> 6;
  const int h = lb & 63;
  const int t = (int)threadIdx.x;

  // ---- Phase A: stage m rows h-1,h,h+1 ----
  for (int idx = t; idx < 3 * 64 * 8; idx += 256) {
    int r = idx >> 9;
    int rem = idx & 511;
    int w = rem >> 3, u = rem & 7;
    int hh = h + r - 1;
    uint4 val = make_uint4(0u, 0u, 0u, 0u);
    if (hh >= 0 && hh < 64)
      val = *(const uint4*)&m_t[(((b * 64 + hh) * 64 + w) * 64) + u * 8];
    *(uint4*)&m_s[(r * 64 + w) * 72 + u * 8] = val;
  }
  __syncthreads();

  const int wave = t >> 6, lane = t & 63;
  const int quad = lane >> 4, col = lane & 15;
  const int nbase = wave * 32;

  const floatx4 z4 = {0.f, 0.f, 0.f, 0.f};
  floatx4 acc[2][4];
#pragma unroll
  for (int i = 0; i < 2; ++i)
#pragma unroll
    for (int p = 0; p < 4; ++p) acc[i][p] = z4;

  const short8 z8 = {0, 0, 0, 0, 0, 0, 0, 0};

#pragma unroll
  for (int tap = 0; tap < 9; ++tap) {
    const int dh = tap / 3, dw = tap % 3;
#pragma unroll
    for (int half = 0; half < 2; ++half) {
      const int mo0 = half * 32;
      short8 a0 = *(const short8*)&a_prep[((tap * 128 + nbase + col) * 64) + mo0 + quad * 8];
      short8 a1 = *(const short8*)&a_prep[((tap * 128 + nbase + 16 + col) * 64) + mo0 + quad * 8];
#pragma unroll
      for (int p = 0; p < 4; ++p) {
        int wsrc = p * 16 + col + dw - 1;
        int wc = min(max(wsrc, 0), 63);
        short8 bf = *(const short8*)&m_s[(dh * 64 + wc) * 72 + mo0 + quad * 8];
        if (wsrc < 0 || wsrc > 63) bf = z8;
        acc[0][p] = __builtin_amdgcn_mfma_f32_16x16x32_bf16(a0, bf, acc[0][p], 0, 0, 0);
        acc[1][p] = __builtin_amdgcn_mfma_f32_16x16x32_bf16(a1, bf, acc[1][p], 0, 0, 0);
      }
    }
  }

  __syncthreads();  // m_s dead; raw takes over the union
#pragma unroll
  for (int i = 0; i < 2; ++i)
#pragma unroll
    for (int p = 0; p < 4; ++p)
#pragma unroll
      for (int r = 0; r < 4; ++r)
        raw[(nbase + i * 16 + quad * 4 + r) * 66 + p * 16 + col] = acc[i][p][r];
  __syncthreads();

  // softmax over kk (n = kk*4+q), q = wave, px = lane
  const int q = wave;
  float v[25];
  float mx = -1e30f;
#pragma unroll
  for (int kk = 0; kk < 25; ++kk) {
    v[kk] = raw[(kk * 4 + q) * 66 + lane] + eb[kk * 4 + q];
    mx = fmaxf(mx, v[kk]);
  }
  float s = 0.f;
#pragma unroll
  for (int kk = 0; kk < 25; ++kk) {
    v[kk] = __expf(v[kk] - mx);
    s += v[kk];
  }
  float inv = 1.f / s;

  __syncthreads();  // raw reads done; wgt_s takes over the union
  {
    const int ohl = q >> 1;
    const int owp = 2 * lane + (q & 1);
#pragma unroll
    for (int kk = 0; kk < 25; ++kk)
      wgt_s[(ohl * 25 + kk) * 128 + owp] = f2bf(v[kk] * inv);
  }
  __syncthreads();

  // ---- Phase B: reassembly, both channel halves ----
  const int wg = t & 15;
  const int cg = t >> 4;
  const int w0 = wg * 4;

  for (int chalf = 0; chalf < 2; ++chalf) {
    const int c0 = chalf * 64 + cg * 4;
    const unsigned short* xb =
        xpad + ((size_t)(b * 128 + c0) * 4896) + h * 72 + w0;

    v2f accB[2][4][4];  // [oh][ch][k]
#pragma unroll
    for (int oh = 0; oh < 2; ++oh)
#pragma unroll
      for (int ch = 0; ch < 4; ++ch)
#pragma unroll
        for (int k = 0; k < 4; ++k) accB[oh][ch][k] = (v2f){0.f, 0.f};

    for (int i = 0; i < 5; ++i) {
      float xr[4][8];
#pragma unroll
      for (int ch = 0; ch < 4; ++ch) {
        uint4 rawv = *(const uint4*)(xb + ch * 4896 + i * 72);
        unpack2(rawv.x, xr[ch][0], xr[ch][1]);
        unpack2(rawv.y, xr[ch][2], xr[ch][3]);
        unpack2(rawv.z, xr[ch][4], xr[ch][5]);
        unpack2(rawv.w, xr[ch][6], xr[ch][7]);
      }
#pragma unroll
      for (int j = 0; j < 5; ++j) {
        const int ij = i * 5 + j;
#pragma unroll
        for (int oh = 0; oh < 2; ++oh) {
          uint4 wr = *(const uint4*)&wgt_s[(oh * 25 + ij) * 128 + w0 * 2];
          v2f wp[4];
          wp[0] = unpack2v(wr.x);
          wp[1] = unpack2v(wr.y);
          wp[2] = unpack2v(wr.z);
          wp[3] = unpack2v(wr.w);
#pragma unroll
          for (int k = 0; k < 4; ++k)
#pragma unroll
            for (int ch = 0; ch < 4; ++ch) {
              float xv = xr[ch][k + j];
              v2f xvv = {xv, xv};
              accB[oh][ch][k] += xvv * wp[k];  // v_pk_fma_f32
            }
        }
      }
    }

#pragma unroll
    for (int ch = 0; ch < 4; ++ch)
#pragma unroll
      for (int oh = 0; oh < 2; ++oh) {
        float* orow =
            out + ((size_t)(b * 128 + c0 + ch) * 128 + (2 * h + oh)) * 128 + w0 * 2;
        float4 f0 = make_float4(accB[oh][ch][0].x, accB[oh][ch][0].y,
                                accB[oh][ch][1].x, accB[oh][ch][1].y);
        float4 f1 = make_float4(accB[oh][ch][2].x, accB[oh][ch][2].y,
                                accB[oh][ch][3].x, accB[oh][ch][3].y);
        *(float4*)orow = f0;
        *(float4*)(orow + 4) = f1;
      }
  }
}

// ---------------------------------------------------------------------------
extern "C" void kernel_launch(void* const* d_in, const int* in_sizes, int n_in,
                              void* d_out, int out_size, void* d_ws, size_t ws_size,
                              hipStream_t stream) {
  (void)in_sizes; (void)n_in; (void)out_size; (void)ws_size;
  const float* x  = (const float*)d_in[0];
  const float* cw = (const float*)d_in[1];
  const float* cb = (const float*)d_in[2];
  const float* ew = (const float*)d_in[3];
  const float* eb = (const float*)d_in[4];
  float* out = (float*)d_out;

  char* wsb = (char*)d_ws;
  unsigned short* m_t    = (unsigned short*)(wsb);               // 4,194,304 B
  unsigned short* a_prep = (unsigned short*)(wsb + 4194304);     //   147,456 B
  unsigned short* xpad   = (unsigned short*)(wsb + 4341760);     // 10,027,008 B
  float*          cwT    = (float*)(wsb + 14368768);             //    32,768 B

  k_prep<<<dim3(832), dim3(256), 0, stream>>>(ew, cw, a_prep, cwT, xpad);
  k_comp_pad<<<dim3(512), dim3(256), 0, stream>>>(x, cwT, cb, m_t, xpad);
  k_main<<<dim3(512), dim3(256), 0, stream>>>(m_t, a_prep, eb, xpad, out);
}